// Round 6
// baseline (3135.425 us; speedup 1.0000x reference)
//
#include <hip/hip_runtime.h>
#include <hip/hip_bf16.h>

#define NN 100000
#define EE 1600000
#define HH 128
#define NDIM 91
#define EDIM 20
#define BB 128
#define EPSF 1e-5f
#define EB 32  // edges per batch in k_edge_mfma

typedef __attribute__((ext_vector_type(8))) short short8v;
typedef __attribute__((ext_vector_type(4))) float f32x4;

__device__ __forceinline__ short f2bs(float x) {
  __hip_bfloat16 b = __float2bfloat16(x);
  return *reinterpret_cast<short*>(&b);
}
__device__ __forceinline__ float us2f(unsigned short u) {
  union { unsigned int i; float f; } x;
  x.i = ((unsigned int)u) << 16;
  return x.f;
}

// ---------------- embed: h = nf @ W + b  (N x 91 @ 91 x 128) ----------------
__global__ __launch_bounds__(256) void k_embed(const float* __restrict__ nf,
                                               const float* __restrict__ W,
                                               const float* __restrict__ b,
                                               float* __restrict__ h) {
  __shared__ float w_s[NDIM * HH];
  __shared__ float b_s[HH];
  __shared__ float a_s[16 * 92];
  for (int i = threadIdx.x; i < NDIM * HH; i += 256) w_s[i] = W[i];
  if (threadIdx.x < HH) b_s[threadIdx.x] = b[threadIdx.x];
  __syncthreads();
  int col = threadIdx.x & 127, rs = threadIdx.x >> 7;
  for (int base = blockIdx.x * 16; base < NN; base += gridDim.x * 16) {
    int nrows = min(16, NN - base);
    int tot = nrows * NDIM;
    for (int i = threadIdx.x; i < tot; i += 256) {
      int r = i / NDIM;
      a_s[r * 92 + (i - r * NDIM)] = nf[(size_t)base * NDIM + i];
    }
    __syncthreads();
    float acc[8];
#pragma unroll
    for (int r = 0; r < 8; r++) acc[r] = 0.f;
    for (int k = 0; k < NDIM; k++) {
      float w = w_s[k * HH + col];
#pragma unroll
      for (int r = 0; r < 8; r++) acc[r] += a_s[(rs * 8 + r) * 92 + k] * w;
    }
#pragma unroll
    for (int r = 0; r < 8; r++) {
      int row = base + rs * 8 + r;
      if (row < NN) h[(size_t)row * HH + col] = acc[r] + b_s[col];
    }
    __syncthreads();
  }
}

// ------- weight transpose+cast: wt[mat][col][k] = W_mat[k*256+col] (bf16) ---
__global__ __launch_bounds__(256) void k_w2bf(const float* __restrict__ Wsrc,
                                              const float* __restrict__ Wdst,
                                              short* __restrict__ wt) {
  int i = blockIdx.x * 256 + threadIdx.x;  // 0..65535
  if (i >= 2 * 256 * 128) return;
  int mat = i >> 15;
  int r = (i >> 7) & 255;
  int k = i & 127;
  const float* W = mat ? Wdst : Wsrc;
  wt[i] = f2bs(W[k * 256 + r]);
}

// ------- edge-weight transpose+cast: Web[c][k] bf16, k=20 -> bias, pad 0 ----
__global__ __launch_bounds__(256) void k_we2bf(const float* __restrict__ We,
                                               const float* __restrict__ bias,
                                               short* __restrict__ Web) {
  int i = blockIdx.x * 256 + threadIdx.x;  // 0..8191
  if (i >= 256 * 32) return;
  int c = i >> 5, k = i & 31;
  float v = (k < EDIM) ? We[k * 256 + c] : (k == EDIM ? bias[c] : 0.f);
  Web[i] = f2bs(v);
}

// ------------- node_mm via MFMA: out = h(bf16) @ W(bf16), f32 acc ----------
__global__ __launch_bounds__(256) void k_node_mm(const float* __restrict__ h,
                                                 const short* __restrict__ wt,
                                                 __hip_bfloat16* __restrict__ hs,
                                                 __hip_bfloat16* __restrict__ hd) {
  __shared__ short hlds[64 * 128];  // 16 KB bf16 A-tile
  int mat = blockIdx.y;
  const short* wtm = wt + mat * 256 * 128;
  __hip_bfloat16* out = mat ? hd : hs;
  int base = blockIdx.x * 64;
  int t = threadIdx.x;
#pragma unroll
  for (int p = 0; p < 4; p++) {
    int e0 = (p * 256 + t) * 8;
    int row = e0 >> 7, col = e0 & 127;
    int gr = base + row;
    float4 f0 = make_float4(0.f, 0.f, 0.f, 0.f), f1 = f0;
    if (gr < NN) {
      f0 = *(const float4*)&h[(size_t)gr * 128 + col];
      f1 = *(const float4*)&h[(size_t)gr * 128 + col + 4];
    }
    short8v u;
    u[0] = f2bs(f0.x); u[1] = f2bs(f0.y); u[2] = f2bs(f0.z); u[3] = f2bs(f0.w);
    u[4] = f2bs(f1.x); u[5] = f2bs(f1.y); u[6] = f2bs(f1.z); u[7] = f2bs(f1.w);
    *(short8v*)&hlds[e0] = u;
  }
  __syncthreads();
  int w = t >> 6, l = t & 63;
  int cl = l & 15, kg = l >> 4;
  short8v a[4];
#pragma unroll
  for (int kk = 0; kk < 4; kk++)
    a[kk] = *(const short8v*)&hlds[(w * 16 + cl) * 128 + kk * 32 + kg * 8];
  f32x4 acc[16];
#pragma unroll
  for (int ct = 0; ct < 16; ct++) acc[ct] = (f32x4)(0.f);
#pragma unroll
  for (int ct = 0; ct < 16; ct++) {
#pragma unroll
    for (int kk = 0; kk < 4; kk++) {
      short8v b = *(const short8v*)&wtm[(ct * 16 + cl) * 128 + kk * 32 + kg * 8];
      acc[ct] = __builtin_amdgcn_mfma_f32_16x16x32_bf16(a[kk], b, acc[ct], 0, 0, 0);
    }
  }
#pragma unroll
  for (int ct = 0; ct < 16; ct++) {
#pragma unroll
    for (int r = 0; r < 4; r++) {
      int gr = base + w * 16 + kg * 4 + r;
      if (gr < NN)
        out[(size_t)gr * 256 + ct * 16 + cl] = __float2bfloat16(acc[ct][r]);
    }
  }
}

// ---------------- counting sort by dst: hist, scan, scatter -----------------
__global__ __launch_bounds__(256) void k_hist(const int* __restrict__ dst,
                                              int* __restrict__ cnt) {
  for (int e = blockIdx.x * 256 + threadIdx.x; e < EE; e += gridDim.x * 256)
    atomicAdd(&cnt[dst[e]], 1);
}

__global__ __launch_bounds__(1024) void k_scan(const int* __restrict__ cnt,
                                               int* __restrict__ off) {
  __shared__ int ps[1024];
  int t = threadIdx.x;
  const int R = (NN + 1023) / 1024;
  int b0 = t * R, b1 = min(NN, b0 + R);
  int s = 0;
  for (int i = b0; i < b1; i++) s += cnt[i];
  ps[t] = s;
  __syncthreads();
  for (int d = 1; d < 1024; d <<= 1) {
    int v = (t >= d) ? ps[t - d] : 0;
    __syncthreads();
    ps[t] += v;
    __syncthreads();
  }
  int run = (t == 0) ? 0 : ps[t - 1];
  for (int i = b0; i < b1; i++) {
    off[i] = run;
    run += cnt[i];
  }
}

__global__ __launch_bounds__(256) void k_scatter(const int* __restrict__ src,
                                                 const int* __restrict__ dst,
                                                 const float* __restrict__ ef,
                                                 int* __restrict__ off,
                                                 int* __restrict__ src_s,
                                                 int* __restrict__ dst_s,
                                                 float* __restrict__ ef_s) {
  for (int e = blockIdx.x * 256 + threadIdx.x; e < EE; e += gridDim.x * 256) {
    int d = dst[e];
    int pos = atomicAdd(&off[d], 1);
    src_s[pos] = src[e];
    dst_s[pos] = d;
    const float4* in = (const float4*)&ef[(size_t)e * EDIM];
    float4* outp = (float4*)&ef_s[(size_t)pos * EDIM];
#pragma unroll
    for (int q = 0; q < 5; q++) outp[q] = in[q];
  }
}

__device__ __forceinline__ float softplus_f(float z) {
  float t = __expf(-fabsf(z));
  float l = __logf(1.f + t);
  return (z > 0.f) ? z + l : l;
}

// ---- edge kernel v4: software-pipelined. Per 32-edge batch:
// {hs-prefetch->regs; MFMA ez=ef@Web} sync {stage(next) || column(cur)} sync
__global__ __launch_bounds__(256, 4) void k_edge_mfma(
    const __hip_bfloat16* __restrict__ hs, const __hip_bfloat16* __restrict__ hd,
    const float* __restrict__ ef_s, const int* __restrict__ src_s,
    const int* __restrict__ dst_s, const short* __restrict__ Web,
    float* __restrict__ agg, int per) {
  __shared__ short ef_lds[EB * 32];    // 2 KB  [edge][k] bf16
  __shared__ float ez_lds[EB][260];    // 33.3 KB f32 (pad 260)
  __shared__ int src_lds[2][EB];
  __shared__ int dst_lds[2][EB];
  int i0 = blockIdx.x * per;
  if (i0 >= EE) return;
  int i1 = min(EE, i0 + per);
  int t = threadIdx.x;
  int w = t >> 6, l = t & 63;
  int cl = l & 15, kg = l >> 4;
  // resident B fragments: this wave's 64 output cols [w*64, w*64+64)
  short8v bfr[4];
#pragma unroll
  for (int ct = 0; ct < 4; ct++)
    bfr[ct] = *(const short8v*)&Web[(w * 64 + ct * 16 + cl) * 32 + kg * 8];
  // column-phase persistent state
  int c = t & 127, hlf = t >> 7, e0l = hlf * 16;
  int cur = dst_s[i0];
  float hd_g = __bfloat162float(hd[(size_t)cur * 256 + c]);
  float hd_p = __bfloat162float(hd[(size_t)cur * 256 + 128 + c]);
  float acc = 0.f;

  // ---- stage helper: ef batch -> bf16 LDS, idx -> buf pb ----
  auto stage = [&](int bs, int pb) {
    for (int i = t; i < EB * EDIM; i += 256) {
      int e = i / EDIM;
      int k = i - e * EDIM;
      float v = 0.f;
      if (bs + e < i1) v = ef_s[(size_t)bs * EDIM + i];
      ef_lds[e * 32 + k] = f2bs(v);
    }
    for (int i = t; i < EB * 12; i += 256) {  // k = 20..31: bias-hook + pad
      int e = i / 12;
      int k = 20 + (i - e * 12);
      ef_lds[e * 32 + k] = (k == EDIM) ? f2bs(1.f) : (short)0;
    }
    if (t < EB) {
      int ge = bs + t;
      src_lds[pb][t] = (ge < i1) ? src_s[ge] : 0;
      dst_lds[pb][t] = (ge < i1) ? dst_s[ge] : -1;
    }
  };

  stage(i0, 0);
  __syncthreads();
  int pb = 0;
  for (int bb = i0; bb < i1; bb += EB, pb ^= 1) {
    // ---- prefetch this batch's hs gathers into registers (issued early) ----
    unsigned short hg[16], hp[16];
#pragma unroll
    for (int e = 0; e < 16; e++) {
      int s = src_lds[pb][e0l + e];
      const unsigned short* row = (const unsigned short*)(hs + (size_t)s * 256);
      hg[e] = row[c];
      hp[e] = row[128 + c];
    }
    // ---- MFMA phase: ez[e][col] = ef[e][:] @ Web[col][:] (f32 to LDS) ----
#pragma unroll
    for (int mt = 0; mt < 2; mt++) {
      short8v a = *(const short8v*)&ef_lds[(mt * 16 + cl) * 32 + kg * 8];
#pragma unroll
      for (int ct = 0; ct < 4; ct++) {
        f32x4 z = __builtin_amdgcn_mfma_f32_16x16x32_bf16(a, bfr[ct], (f32x4)(0.f), 0, 0, 0);
#pragma unroll
        for (int r = 0; r < 4; r++)
          ez_lds[mt * 16 + kg * 4 + r][w * 64 + ct * 16 + cl] = z[r];
      }
    }
    __syncthreads();
    // ---- stage next batch (overlaps column compute) ----
    stage(bb + EB, pb ^ 1);
    // ---- column phase: 2 halves x 128 cols; 16 edges each; register runs ----
#pragma unroll
    for (int e = 0; e < 16; e++) {
      int ge = bb + e0l + e;
      if (ge >= i1) break;  // wave-uniform
      int d = dst_lds[pb][e0l + e];
      if (d != cur) {  // wave-uniform
        atomicAdd(&agg[(size_t)cur * HH + c], acc);
        acc = 0.f;
        cur = d;
        hd_g = __bfloat162float(hd[(size_t)cur * 256 + c]);
        hd_p = __bfloat162float(hd[(size_t)cur * 256 + 128 + c]);
      }
      float zg = ez_lds[e0l + e][c] + us2f(hg[e]) + hd_g;
      float zp = ez_lds[e0l + e][128 + c] + us2f(hp[e]) + hd_p;
      acc += __fdividef(softplus_f(zp), 1.f + __expf(-zg));
    }
    __syncthreads();
  }
  atomicAdd(&agg[(size_t)cur * HH + c], acc);
}

// ---------------- BN stats: per-column sum & sumsq over N rows --------------
__global__ __launch_bounds__(256) void k_bn_stats(const float* __restrict__ agg,
                                                  float* __restrict__ stats) {
  int col = threadIdx.x & 127, hlf = threadIdx.x >> 7;
  float s = 0.f, sq = 0.f;
  for (int row = blockIdx.x * 2 + hlf; row < NN; row += gridDim.x * 2) {
    float v = agg[(size_t)row * HH + col];
    s += v; sq += v * v;
  }
  __shared__ float ls[256], lq[256];
  ls[threadIdx.x] = s; lq[threadIdx.x] = sq;
  __syncthreads();
  if (hlf == 0) {
    atomicAdd(&stats[col], ls[col] + ls[col + 128]);
    atomicAdd(&stats[128 + col], lq[col] + lq[col + 128]);
  }
}

__global__ void k_bn_fin(float* stats, const float* __restrict__ gam,
                         const float* __restrict__ bet) {
  int c = threadIdx.x;
  if (c >= HH) return;
  float mean = stats[c] / (float)NN;
  float var = stats[HH + c] / (float)NN - mean * mean;
  float sc = rsqrtf(var + EPSF) * gam[c];
  stats[c] = sc;
  stats[HH + c] = bet[c] - mean * sc;
}

// ---------------- h = relu(h + agg*scale + shift) ---------------------------
__global__ __launch_bounds__(256) void k_update(float* __restrict__ h,
                                                const float* __restrict__ agg,
                                                const float* __restrict__ stats) {
  for (size_t i = (size_t)blockIdx.x * blockDim.x + threadIdx.x; i < (size_t)NN * HH;
       i += (size_t)gridDim.x * blockDim.x) {
    int c = (int)(i & 127);
    float v = h[i] + agg[i] * stats[c] + stats[128 + c];
    h[i] = fmaxf(v, 0.f);
  }
}

// ---------------- pooling: contiguous chunk per block, register acc ---------
__global__ void k_pool(const float* __restrict__ h, const int* __restrict__ batch,
                       float* __restrict__ g, float* __restrict__ gcnt) {
  int col = threadIdx.x;  // 128
  int chunk = (NN + gridDim.x - 1) / gridDim.x;
  int n0 = blockIdx.x * chunk, n1 = min(NN, n0 + chunk);
  if (n0 >= n1) return;
  int cur = batch[n0];
  float acc = 0.f, cnt = 0.f;
  for (int n = n0; n < n1; n++) {
    int bb = batch[n];
    if (bb != cur) {
      atomicAdd(&g[cur * HH + col], acc);
      if (col == 0) atomicAdd(&gcnt[cur], cnt);
      acc = 0.f; cnt = 0.f; cur = bb;
    }
    acc += h[(size_t)n * HH + col];
    cnt += 1.f;
  }
  atomicAdd(&g[cur * HH + col], acc);
  if (col == 0) atomicAdd(&gcnt[cur], cnt);
}

// ---------------- final head: mean-pool norm, fc1, BN, relu, out ------------
__global__ __launch_bounds__(256) void k_final(float* __restrict__ g,
                                               const float* __restrict__ gcnt,
                                               const float* __restrict__ fc1w,
                                               const float* __restrict__ fc1b,
                                               const float* __restrict__ gam,
                                               const float* __restrict__ bet,
                                               const float* __restrict__ ow,
                                               const float* __restrict__ ob,
                                               float* __restrict__ out) {
  __shared__ float w_s[HH * HH];
  __shared__ float y_s[BB * HH];
  __shared__ float ls[256], lq[256];
  for (int i = threadIdx.x; i < HH * HH; i += 256) w_s[i] = fc1w[i];
  for (int i = threadIdx.x; i < BB * HH; i += 256) {
    int r = i >> 7;
    g[i] = g[i] / fmaxf(gcnt[r], 1.f);
  }
  __syncthreads();
  int c = threadIdx.x & 127, h2 = threadIdx.x >> 7;
  for (int rr = 0; rr < 64; rr++) {
    int r = h2 * 64 + rr;
    float acc = fc1b[c];
    for (int k = 0; k < HH; k++) acc += g[r * HH + k] * w_s[k * HH + c];
    y_s[r * HH + c] = acc;
  }
  __syncthreads();
  float s = 0.f, sq = 0.f;
  for (int rr = 0; rr < 64; rr++) {
    float v = y_s[(h2 * 64 + rr) * HH + c];
    s += v; sq += v * v;
  }
  ls[threadIdx.x] = s; lq[threadIdx.x] = sq;
  __syncthreads();
  if (h2 == 0) {
    float ss = ls[c] + ls[c + 128], qq = lq[c] + lq[c + 128];
    float mean = ss / (float)BB, var = qq / (float)BB - mean * mean;
    float sc = rsqrtf(var + EPSF) * gam[c];
    ls[c] = sc;
    lq[c] = bet[c] - mean * sc;
  }
  __syncthreads();
  for (int rr = 0; rr < 64; rr++) {
    int r = h2 * 64 + rr;
    y_s[r * HH + c] = fmaxf(y_s[r * HH + c] * ls[c] + lq[c], 0.f);
  }
  __syncthreads();
  int r2 = threadIdx.x >> 1, hf = threadIdx.x & 1;
  float acc = 0.f;
  for (int k = hf * 64; k < hf * 64 + 64; k++) acc += y_s[r2 * HH + k] * ow[k];
  __syncthreads();
  ls[threadIdx.x] = acc;
  __syncthreads();
  if (hf == 0) out[r2] = ls[threadIdx.x] + ls[threadIdx.x + 1] + ob[0];
}

extern "C" void kernel_launch(void* const* d_in, const int* in_sizes, int n_in,
                              void* d_out, int out_size, void* d_ws, size_t ws_size,
                              hipStream_t stream) {
  (void)in_sizes; (void)n_in; (void)out_size; (void)ws_size;
  const float* node_feats = (const float*)d_in[0];
  const int* edge_index = (const int*)d_in[1];
  const float* edge_feats = (const float*)d_in[2];
  const int* batch = (const int*)d_in[3];
  const float* embed_w = (const float*)d_in[4];
  const float* embed_b = (const float*)d_in[5];
  const float* conv_wsrc = (const float*)d_in[6];
  const float* conv_wdst = (const float*)d_in[7];
  const float* conv_we = (const float*)d_in[8];
  const float* conv_b = (const float*)d_in[9];
  const float* bn_gamma = (const float*)d_in[10];
  const float* bn_beta = (const float*)d_in[11];
  const float* fc1_w = (const float*)d_in[12];
  const float* fc1_b = (const float*)d_in[13];
  const float* fc_bn_gamma = (const float*)d_in[14];
  const float* fc_bn_beta = (const float*)d_in[15];
  const float* out_w = (const float*)d_in[16];
  const float* out_b = (const float*)d_in[17];

  char* ws = (char*)d_ws;
  size_t o = 0;
  float* h = (float*)(ws + o);            o += (size_t)NN * HH * 4;
  __hip_bfloat16* hs = (__hip_bfloat16*)(ws + o); o += (size_t)NN * 256 * 2;
  __hip_bfloat16* hd = (__hip_bfloat16*)(ws + o); o += (size_t)NN * 256 * 2;
  float* agg = (float*)(ws + o);          o += (size_t)NN * HH * 4;
  float* ef_s = (float*)(ws + o);         o += (size_t)EE * EDIM * 4;
  int* src_s = (int*)(ws + o);            o += (size_t)EE * 4;
  int* dst_s = (int*)(ws + o);            o += (size_t)EE * 4;
  int* cnt = (int*)(ws + o);              o += (size_t)NN * 4;
  int* off = (int*)(ws + o);              o += (size_t)NN * 4;
  short* wt = (short*)(ws + o);           o += (size_t)2 * 256 * 128 * 2;
  short* Web = (short*)(ws + o);          o += (size_t)256 * 32 * 2;
  float* stats = (float*)(ws + o);        o += 256 * 4;
  float* g = (float*)(ws + o);            o += (size_t)BB * HH * 4;
  float* gcnt = (float*)(ws + o);         o += BB * 4;

  const int* src = edge_index;
  const int* dst = edge_index + EE;

  // one-time per launch: counting sort of edges by dst (reused by all layers)
  hipMemsetAsync(cnt, 0, (size_t)NN * 4, stream);
  k_hist<<<2048, 256, 0, stream>>>(dst, cnt);
  k_scan<<<1, 1024, 0, stream>>>(cnt, off);
  k_scatter<<<2048, 256, 0, stream>>>(src, dst, edge_feats, off, src_s, dst_s, ef_s);

  k_embed<<<512, 256, 0, stream>>>(node_feats, embed_w, embed_b, h);

  // 2048 blocks x 800 edges: every active block has exactly 25 full batches
  const int nblk = 2048;
  const int per = (((EE + nblk - 1) / nblk) + EB - 1) / EB * EB;  // 800

  for (int i = 0; i < 3; i++) {
    k_w2bf<<<256, 256, 0, stream>>>(conv_wsrc + (size_t)i * HH * 256,
                                    conv_wdst + (size_t)i * HH * 256, wt);
    k_we2bf<<<32, 256, 0, stream>>>(conv_we + (size_t)i * EDIM * 256,
                                    conv_b + (size_t)i * 256, Web);
    k_node_mm<<<dim3((NN + 63) / 64, 2), 256, 0, stream>>>(h, wt, hs, hd);
    hipMemsetAsync(agg, 0, (size_t)NN * HH * 4, stream);
    hipMemsetAsync(stats, 0, 256 * 4, stream);
    k_edge_mfma<<<nblk, 256, 0, stream>>>(hs, hd, ef_s, src_s, dst_s, Web, agg, per);
    k_bn_stats<<<1024, 256, 0, stream>>>(agg, stats);
    k_bn_fin<<<1, 128, 0, stream>>>(stats, bn_gamma + i * HH, bn_beta + i * HH);
    k_update<<<2048, 256, 0, stream>>>(h, agg, stats);
  }

  hipMemsetAsync(g, 0, (size_t)BB * HH * 4, stream);
  hipMemsetAsync(gcnt, 0, BB * 4, stream);
  k_pool<<<256, 128, 0, stream>>>(h, batch, g, gcnt);
  k_final<<<1, 256, 0, stream>>>(g, gcnt, fc1_w, fc1_b, fc_bn_gamma, fc_bn_beta,
                                 out_w, out_b, (float*)d_out);
}

// Round 7
// 2127.587 us; speedup vs baseline: 1.4737x; 1.4737x over previous
//
#include <hip/hip_runtime.h>
#include <hip/hip_bf16.h>

#define NN 100000
#define EE 1600000
#define HH 128
#define NDIM 91
#define EDIM 20
#define BB 128
#define EPSF 1e-5f
#define NBLK 2048
#define PER 800                 // edges per block (4 kg-subranges of 200)
#define ECAP (NBLK * PER)       // 1,638,400 (padded)
#define LN2I 1.44269504f

typedef __attribute__((ext_vector_type(8))) short short8v;
typedef __attribute__((ext_vector_type(4))) float f32x4;

__device__ __forceinline__ short f2bs(float x) {
  __hip_bfloat16 b = __float2bfloat16(x);
  return *reinterpret_cast<short*>(&b);
}
__device__ __forceinline__ float bl(unsigned int u) {  // lo bf16 -> f32
  union { unsigned int i; float f; } x; x.i = u << 16; return x.f;
}
__device__ __forceinline__ float bh(unsigned int u) {  // hi bf16 -> f32
  union { unsigned int i; float f; } x; x.i = u & 0xffff0000u; return x.f;
}

// ---------------- embed: h = nf @ W + b  (N x 91 @ 91 x 128) ----------------
__global__ __launch_bounds__(256) void k_embed(const float* __restrict__ nf,
                                               const float* __restrict__ W,
                                               const float* __restrict__ b,
                                               float* __restrict__ h) {
  __shared__ float w_s[NDIM * HH];
  __shared__ float b_s[HH];
  __shared__ float a_s[16 * 92];
  for (int i = threadIdx.x; i < NDIM * HH; i += 256) w_s[i] = W[i];
  if (threadIdx.x < HH) b_s[threadIdx.x] = b[threadIdx.x];
  __syncthreads();
  int col = threadIdx.x & 127, rs = threadIdx.x >> 7;
  for (int base = blockIdx.x * 16; base < NN; base += gridDim.x * 16) {
    int nrows = min(16, NN - base);
    int tot = nrows * NDIM;
    for (int i = threadIdx.x; i < tot; i += 256) {
      int r = i / NDIM;
      a_s[r * 92 + (i - r * NDIM)] = nf[(size_t)base * NDIM + i];
    }
    __syncthreads();
    float acc[8];
#pragma unroll
    for (int r = 0; r < 8; r++) acc[r] = 0.f;
    for (int k = 0; k < NDIM; k++) {
      float w = w_s[k * HH + col];
#pragma unroll
      for (int r = 0; r < 8; r++) acc[r] += a_s[(rs * 8 + r) * 92 + k] * w;
    }
#pragma unroll
    for (int r = 0; r < 8; r++) {
      int row = base + rs * 8 + r;
      if (row < NN) h[(size_t)row * HH + col] = acc[r] + b_s[col];
    }
    __syncthreads();
  }
}

// ------- weight transpose+cast: wt[mat][col][k] = W_mat[k*256+col] (bf16) ---
__global__ __launch_bounds__(256) void k_w2bf(const float* __restrict__ Wsrc,
                                              const float* __restrict__ Wdst,
                                              short* __restrict__ wt) {
  int i = blockIdx.x * 256 + threadIdx.x;  // 0..65535
  if (i >= 2 * 256 * 128) return;
  int mat = i >> 15;
  int r = (i >> 7) & 255;
  int k = i & 127;
  const float* W = mat ? Wdst : Wsrc;
  wt[i] = f2bs(W[k * 256 + r]);
}

// --- edge-weight: Web[c][k] bf16 (k=20 -> bias, pad 0), scaled:
// --- gate cols (c<128) * -1/ln2, soft cols * +1/ln2 (exp2 formulation) ------
__global__ __launch_bounds__(256) void k_we2bf(const float* __restrict__ We,
                                               const float* __restrict__ bias,
                                               short* __restrict__ Web) {
  int i = blockIdx.x * 256 + threadIdx.x;  // 0..8191
  if (i >= 256 * 32) return;
  int c = i >> 5, k = i & 31;
  float v = (k < EDIM) ? We[k * 256 + c] : (k == EDIM ? bias[c] : 0.f);
  float sc = (c < 128) ? -LN2I : LN2I;
  Web[i] = f2bs(v * sc);
}

// ------------- node_mm via MFMA: paired/scaled output ----------------------
// out word (node, c) = pack( bf16(-1.4427*z_gate[c]), bf16(+1.4427*z_soft[c]) )
__global__ __launch_bounds__(256) void k_node_mm(const float* __restrict__ h,
                                                 const short* __restrict__ wt,
                                                 unsigned int* __restrict__ hs2,
                                                 unsigned int* __restrict__ hd2) {
  __shared__ short hlds[64 * 128];  // 16 KB bf16 A-tile
  int mat = blockIdx.y;
  const short* wtm = wt + mat * 256 * 128;
  unsigned int* out = mat ? hd2 : hs2;
  int base = blockIdx.x * 64;
  int t = threadIdx.x;
#pragma unroll
  for (int p = 0; p < 4; p++) {
    int e0 = (p * 256 + t) * 8;
    int row = e0 >> 7, col = e0 & 127;
    int gr = base + row;
    float4 f0 = make_float4(0.f, 0.f, 0.f, 0.f), f1 = f0;
    if (gr < NN) {
      f0 = *(const float4*)&h[(size_t)gr * 128 + col];
      f1 = *(const float4*)&h[(size_t)gr * 128 + col + 4];
    }
    short8v u;
    u[0] = f2bs(f0.x); u[1] = f2bs(f0.y); u[2] = f2bs(f0.z); u[3] = f2bs(f0.w);
    u[4] = f2bs(f1.x); u[5] = f2bs(f1.y); u[6] = f2bs(f1.z); u[7] = f2bs(f1.w);
    *(short8v*)&hlds[e0] = u;
  }
  __syncthreads();
  int w = t >> 6, l = t & 63;
  int cl = l & 15, kg = l >> 4;
  short8v a[4];
#pragma unroll
  for (int kk = 0; kk < 4; kk++)
    a[kk] = *(const short8v*)&hlds[(w * 16 + cl) * 128 + kk * 32 + kg * 8];
  f32x4 acc[16];
#pragma unroll
  for (int ct = 0; ct < 16; ct++) acc[ct] = (f32x4)(0.f);
#pragma unroll
  for (int ct = 0; ct < 16; ct++) {
#pragma unroll
    for (int kk = 0; kk < 4; kk++) {
      short8v b = *(const short8v*)&wtm[(ct * 16 + cl) * 128 + kk * 32 + kg * 8];
      acc[ct] = __builtin_amdgcn_mfma_f32_16x16x32_bf16(a[kk], b, acc[ct], 0, 0, 0);
    }
  }
  // pair gate col c (ct<8) with soft col c+128 (ct+8) into one dword
#pragma unroll
  for (int ct = 0; ct < 8; ct++) {
#pragma unroll
    for (int r = 0; r < 4; r++) {
      int gr = base + w * 16 + kg * 4 + r;
      if (gr < NN) {
        unsigned short g = (unsigned short)f2bs(-LN2I * acc[ct][r]);
        unsigned short s = (unsigned short)f2bs(LN2I * acc[ct + 8][r]);
        out[(size_t)gr * 128 + ct * 16 + cl] =
            (unsigned int)g | ((unsigned int)s << 16);
      }
    }
  }
}

// ---------------- counting sort by dst: hist, scan, scatter -----------------
__global__ __launch_bounds__(256) void k_hist(const int* __restrict__ dst,
                                              int* __restrict__ cnt) {
  for (int e = blockIdx.x * 256 + threadIdx.x; e < EE; e += gridDim.x * 256)
    atomicAdd(&cnt[dst[e]], 1);
}

__global__ __launch_bounds__(1024) void k_scan(const int* __restrict__ cnt,
                                               int* __restrict__ off) {
  __shared__ int ps[1024];
  int t = threadIdx.x;
  const int R = (NN + 1023) / 1024;
  int b0 = t * R, b1 = min(NN, b0 + R);
  int s = 0;
  for (int i = b0; i < b1; i++) s += cnt[i];
  ps[t] = s;
  __syncthreads();
  for (int d = 1; d < 1024; d <<= 1) {
    int v = (t >= d) ? ps[t - d] : 0;
    __syncthreads();
    ps[t] += v;
    __syncthreads();
  }
  int run = (t == 0) ? 0 : ps[t - 1];
  for (int i = b0; i < b1; i++) {
    off[i] = run;
    run += cnt[i];
  }
}

// scatter: sorted idx arrays + ef rows pre-cast to bf16 [32] (k20=1.0 bias hook)
__global__ __launch_bounds__(256) void k_scatter(const int* __restrict__ src,
                                                 const int* __restrict__ dst,
                                                 const float* __restrict__ ef,
                                                 int* __restrict__ off,
                                                 int* __restrict__ src_s,
                                                 int* __restrict__ dst_s,
                                                 short* __restrict__ efp) {
  for (int e = blockIdx.x * 256 + threadIdx.x; e < EE; e += gridDim.x * 256) {
    int d = dst[e];
    int pos = atomicAdd(&off[d], 1);
    src_s[pos] = src[e];
    dst_s[pos] = d;
    const float4* in = (const float4*)&ef[(size_t)e * EDIM];
    float4 q0 = in[0], q1 = in[1], q2 = in[2], q3 = in[3], q4 = in[4];
    short8v u0, u1, u2, u3;
    u0[0] = f2bs(q0.x); u0[1] = f2bs(q0.y); u0[2] = f2bs(q0.z); u0[3] = f2bs(q0.w);
    u0[4] = f2bs(q1.x); u0[5] = f2bs(q1.y); u0[6] = f2bs(q1.z); u0[7] = f2bs(q1.w);
    u1[0] = f2bs(q2.x); u1[1] = f2bs(q2.y); u1[2] = f2bs(q2.z); u1[3] = f2bs(q2.w);
    u1[4] = f2bs(q3.x); u1[5] = f2bs(q3.y); u1[6] = f2bs(q3.z); u1[7] = f2bs(q3.w);
    u2[0] = f2bs(q4.x); u2[1] = f2bs(q4.y); u2[2] = f2bs(q4.z); u2[3] = f2bs(q4.w);
    u2[4] = f2bs(1.0f); u2[5] = 0; u2[6] = 0; u2[7] = 0;
    u3 = (short8v)(short)0;
    short8v* op = (short8v*)&efp[(size_t)pos * 32];
    op[0] = u0; op[1] = u1; op[2] = u2; op[3] = u3;
  }
}

// pad tail [EE, ECAP): dst=-2 sentinel, zero ef rows
__global__ __launch_bounds__(256) void k_padtail(int* __restrict__ src_s,
                                                 int* __restrict__ dst_s,
                                                 short* __restrict__ efp) {
  int e = EE + blockIdx.x * 256 + threadIdx.x;
  if (e >= ECAP) return;
  src_s[e] = 0;
  dst_s[e] = -2;
  short8v z = (short8v)(short)0;
  short8v* op = (short8v*)&efp[(size_t)e * 32];
  op[0] = z; op[1] = z; op[2] = z; op[3] = z;
}

// ---- edge kernel v5: barrier-free, zero LDS.
// Wave w owns gate cols [w*32,w*32+32) + their soft partners; per 16-edge tile
// 4 MFMAs give each lane z_gate/z_soft for its own (edge,col) pairs in-register.
// Edge->tile-row permutation makes each lane's edges a contiguous run of the
// dst-sorted order -> per-lane register segment sums, rare atomic flushes.
// msg' = log2(1+2^zs') * rcp(1+2^zgN) = msg/ln2 (BN absorbs the scale).
__global__ __launch_bounds__(256) void k_edge_v5(
    const unsigned int* __restrict__ hs2, const unsigned int* __restrict__ hd2,
    const short* __restrict__ efp, const int* __restrict__ srcp,
    const int* __restrict__ dstp, const short* __restrict__ Web,
    float* __restrict__ agg) {
  const int i0 = blockIdx.x * PER;
  int t = threadIdx.x;
  int w = t >> 6, l = t & 63, cl = l & 15, kg = l >> 4;
  int c0 = w * 32 + cl, c1 = c0 + 16;
  short8v bg0 = *(const short8v*)&Web[c0 * 32 + kg * 8];
  short8v bg1 = *(const short8v*)&Web[c1 * 32 + kg * 8];
  short8v bs0 = *(const short8v*)&Web[(128 + c0) * 32 + kg * 8];
  short8v bs1 = *(const short8v*)&Web[(128 + c1) * 32 + kg * 8];
  int cur = -1;
  float acc0 = 0.f, acc1 = 0.f;
  float hg0 = 0.f, hp0 = 0.f, hg1 = 0.f, hp1 = 0.f;
  const int o_a_base = i0 + (cl >> 2) * 200 + (cl & 3);
  const int o_e_base = i0 + kg * 200;
  for (int it = 0; it < 50; ++it) {
    int off4 = it * 4;
    short8v a = *(const short8v*)&efp[(o_a_base + off4) * 32 + kg * 8];
    f32x4 zgv0 = __builtin_amdgcn_mfma_f32_16x16x32_bf16(a, bg0, (f32x4)(0.f), 0, 0, 0);
    f32x4 zgv1 = __builtin_amdgcn_mfma_f32_16x16x32_bf16(a, bg1, (f32x4)(0.f), 0, 0, 0);
    f32x4 zsv0 = __builtin_amdgcn_mfma_f32_16x16x32_bf16(a, bs0, (f32x4)(0.f), 0, 0, 0);
    f32x4 zsv1 = __builtin_amdgcn_mfma_f32_16x16x32_bf16(a, bs1, (f32x4)(0.f), 0, 0, 0);
    int o_e = o_e_base + off4;
#pragma unroll
    for (int r = 0; r < 4; ++r) {
      int o = o_e + r;
      int s = srcp[o];
      int d = dstp[o];
      if (d != cur) {  // per-lane divergent, rare (~1/16 edges)
        if (cur >= 0) {
          atomicAdd(&agg[cur * HH + c0], acc0);
          atomicAdd(&agg[cur * HH + c1], acc1);
        }
        acc0 = 0.f; acc1 = 0.f;
        cur = d;
        if (d >= 0) {
          unsigned int x0 = hd2[(d << 7) + c0];
          unsigned int x1 = hd2[(d << 7) + c1];
          hg0 = bl(x0); hp0 = bh(x0);
          hg1 = bl(x1); hp1 = bh(x1);
        }
      }
      unsigned int u0 = hs2[(s << 7) + c0];
      unsigned int u1 = hs2[(s << 7) + c1];
      float zgN0 = zgv0[r] + bl(u0) + hg0;
      float zsp0 = zsv0[r] + bh(u0) + hp0;
      float zgN1 = zgv1[r] + bl(u1) + hg1;
      float zsp1 = zsv1[r] + bh(u1) + hp1;
      float sp0 = __builtin_amdgcn_logf(1.f + __builtin_amdgcn_exp2f(zsp0));
      float sp1 = __builtin_amdgcn_logf(1.f + __builtin_amdgcn_exp2f(zsp1));
      acc0 += sp0 * __builtin_amdgcn_rcpf(1.f + __builtin_amdgcn_exp2f(zgN0));
      acc1 += sp1 * __builtin_amdgcn_rcpf(1.f + __builtin_amdgcn_exp2f(zgN1));
    }
  }
  if (cur >= 0) {
    atomicAdd(&agg[cur * HH + c0], acc0);
    atomicAdd(&agg[cur * HH + c1], acc1);
  }
}

// ---------------- BN stats: per-column sum & sumsq over N rows --------------
__global__ __launch_bounds__(256) void k_bn_stats(const float* __restrict__ agg,
                                                  float* __restrict__ stats) {
  int col = threadIdx.x & 127, hlf = threadIdx.x >> 7;
  float s = 0.f, sq = 0.f;
  for (int row = blockIdx.x * 2 + hlf; row < NN; row += gridDim.x * 2) {
    float v = agg[(size_t)row * HH + col];
    s += v; sq += v * v;
  }
  __shared__ float ls[256], lq[256];
  ls[threadIdx.x] = s; lq[threadIdx.x] = sq;
  __syncthreads();
  if (hlf == 0) {
    atomicAdd(&stats[col], ls[col] + ls[col + 128]);
    atomicAdd(&stats[128 + col], lq[col] + lq[col + 128]);
  }
}

__global__ void k_bn_fin(float* stats, const float* __restrict__ gam,
                         const float* __restrict__ bet) {
  int c = threadIdx.x;
  if (c >= HH) return;
  float mean = stats[c] / (float)NN;
  float var = stats[HH + c] / (float)NN - mean * mean;
  float sc = rsqrtf(var + EPSF) * gam[c];
  stats[c] = sc;
  stats[HH + c] = bet[c] - mean * sc;
}

// ---------------- h = relu(h + agg*scale + shift) ---------------------------
__global__ __launch_bounds__(256) void k_update(float* __restrict__ h,
                                                const float* __restrict__ agg,
                                                const float* __restrict__ stats) {
  for (size_t i = (size_t)blockIdx.x * blockDim.x + threadIdx.x; i < (size_t)NN * HH;
       i += (size_t)gridDim.x * blockDim.x) {
    int c = (int)(i & 127);
    float v = h[i] + agg[i] * stats[c] + stats[128 + c];
    h[i] = fmaxf(v, 0.f);
  }
}

// ---------------- pooling: contiguous chunk per block, register acc ---------
__global__ void k_pool(const float* __restrict__ h, const int* __restrict__ batch,
                       float* __restrict__ g, float* __restrict__ gcnt) {
  int col = threadIdx.x;  // 128
  int chunk = (NN + gridDim.x - 1) / gridDim.x;
  int n0 = blockIdx.x * chunk, n1 = min(NN, n0 + chunk);
  if (n0 >= n1) return;
  int cur = batch[n0];
  float acc = 0.f, cnt = 0.f;
  for (int n = n0; n < n1; n++) {
    int bb = batch[n];
    if (bb != cur) {
      atomicAdd(&g[cur * HH + col], acc);
      if (col == 0) atomicAdd(&gcnt[cur], cnt);
      acc = 0.f; cnt = 0.f; cur = bb;
    }
    acc += h[(size_t)n * HH + col];
    cnt += 1.f;
  }
  atomicAdd(&g[cur * HH + col], acc);
  if (col == 0) atomicAdd(&gcnt[cur], cnt);
}

// ---------------- final head: mean-pool norm, fc1, BN, relu, out ------------
__global__ __launch_bounds__(256) void k_final(float* __restrict__ g,
                                               const float* __restrict__ gcnt,
                                               const float* __restrict__ fc1w,
                                               const float* __restrict__ fc1b,
                                               const float* __restrict__ gam,
                                               const float* __restrict__ bet,
                                               const float* __restrict__ ow,
                                               const float* __restrict__ ob,
                                               float* __restrict__ out) {
  __shared__ float w_s[HH * HH];
  __shared__ float y_s[BB * HH];
  __shared__ float ls[256], lq[256];
  for (int i = threadIdx.x; i < HH * HH; i += 256) w_s[i] = fc1w[i];
  for (int i = threadIdx.x; i < BB * HH; i += 256) {
    int r = i >> 7;
    g[i] = g[i] / fmaxf(gcnt[r], 1.f);
  }
  __syncthreads();
  int c = threadIdx.x & 127, h2 = threadIdx.x >> 7;
  for (int rr = 0; rr < 64; rr++) {
    int r = h2 * 64 + rr;
    float acc = fc1b[c];
    for (int k = 0; k < HH; k++) acc += g[r * HH + k] * w_s[k * HH + c];
    y_s[r * HH + c] = acc;
  }
  __syncthreads();
  float s = 0.f, sq = 0.f;
  for (int rr = 0; rr < 64; rr++) {
    float v = y_s[(h2 * 64 + rr) * HH + c];
    s += v; sq += v * v;
  }
  ls[threadIdx.x] = s; lq[threadIdx.x] = sq;
  __syncthreads();
  if (h2 == 0) {
    float ss = ls[c] + ls[c + 128], qq = lq[c] + lq[c + 128];
    float mean = ss / (float)BB, var = qq / (float)BB - mean * mean;
    float sc = rsqrtf(var + EPSF) * gam[c];
    ls[c] = sc;
    lq[c] = bet[c] - mean * sc;
  }
  __syncthreads();
  for (int rr = 0; rr < 64; rr++) {
    int r = h2 * 64 + rr;
    y_s[r * HH + c] = fmaxf(y_s[r * HH + c] * ls[c] + lq[c], 0.f);
  }
  __syncthreads();
  int r2 = threadIdx.x >> 1, hf = threadIdx.x & 1;
  float acc = 0.f;
  for (int k = hf * 64; k < hf * 64 + 64; k++) acc += y_s[r2 * HH + k] * ow[k];
  __syncthreads();
  ls[threadIdx.x] = acc;
  __syncthreads();
  if (hf == 0) out[r2] = ls[threadIdx.x] + ls[threadIdx.x + 1] + ob[0];
}

extern "C" void kernel_launch(void* const* d_in, const int* in_sizes, int n_in,
                              void* d_out, int out_size, void* d_ws, size_t ws_size,
                              hipStream_t stream) {
  (void)in_sizes; (void)n_in; (void)out_size; (void)ws_size;
  const float* node_feats = (const float*)d_in[0];
  const int* edge_index = (const int*)d_in[1];
  const float* edge_feats = (const float*)d_in[2];
  const int* batch = (const int*)d_in[3];
  const float* embed_w = (const float*)d_in[4];
  const float* embed_b = (const float*)d_in[5];
  const float* conv_wsrc = (const float*)d_in[6];
  const float* conv_wdst = (const float*)d_in[7];
  const float* conv_we = (const float*)d_in[8];
  const float* conv_b = (const float*)d_in[9];
  const float* bn_gamma = (const float*)d_in[10];
  const float* bn_beta = (const float*)d_in[11];
  const float* fc1_w = (const float*)d_in[12];
  const float* fc1_b = (const float*)d_in[13];
  const float* fc_bn_gamma = (const float*)d_in[14];
  const float* fc_bn_beta = (const float*)d_in[15];
  const float* out_w = (const float*)d_in[16];
  const float* out_b = (const float*)d_in[17];

  char* ws = (char*)d_ws;
  size_t o = 0;
  float* h = (float*)(ws + o);              o += (size_t)NN * HH * 4;      // 51.2 MB
  unsigned int* hs2 = (unsigned int*)(ws + o); o += (size_t)NN * 128 * 4;  // 51.2 MB
  unsigned int* hd2 = (unsigned int*)(ws + o); o += (size_t)NN * 128 * 4;  // 51.2 MB
  float* agg = (float*)(ws + o);            o += (size_t)NN * HH * 4;      // 51.2 MB
  short* efp = (short*)(ws + o);            o += (size_t)ECAP * 32 * 2;    // 104.9 MB
  int* src_s = (int*)(ws + o);              o += (size_t)ECAP * 4;         // 6.6 MB
  int* dst_s = (int*)(ws + o);              o += (size_t)ECAP * 4;         // 6.6 MB
  int* cnt = (int*)(ws + o);                o += (size_t)NN * 4;
  int* off = (int*)(ws + o);                o += (size_t)NN * 4;
  short* wt = (short*)(ws + o);             o += (size_t)2 * 256 * 128 * 2;
  short* Web = (short*)(ws + o);            o += (size_t)256 * 32 * 2;
  float* stats = (float*)(ws + o);          o += 256 * 4;
  float* g = (float*)(ws + o);              o += (size_t)BB * HH * 4;
  float* gcnt = (float*)(ws + o);           o += BB * 4;

  const int* src = edge_index;
  const int* dst = edge_index + EE;

  // one-time: counting sort by dst + ef pre-cast/pad (reused by all layers)
  hipMemsetAsync(cnt, 0, (size_t)NN * 4, stream);
  k_hist<<<2048, 256, 0, stream>>>(dst, cnt);
  k_scan<<<1, 1024, 0, stream>>>(cnt, off);
  k_scatter<<<2048, 256, 0, stream>>>(src, dst, edge_feats, off, src_s, dst_s, efp);
  k_padtail<<<(ECAP - EE + 255) / 256, 256, 0, stream>>>(src_s, dst_s, efp);

  k_embed<<<512, 256, 0, stream>>>(node_feats, embed_w, embed_b, h);

  for (int i = 0; i < 3; i++) {
    k_w2bf<<<256, 256, 0, stream>>>(conv_wsrc + (size_t)i * HH * 256,
                                    conv_wdst + (size_t)i * HH * 256, wt);
    k_we2bf<<<32, 256, 0, stream>>>(conv_we + (size_t)i * EDIM * 256,
                                    conv_b + (size_t)i * 256, Web);
    k_node_mm<<<dim3((NN + 63) / 64, 2), 256, 0, stream>>>(h, wt, hs2, hd2);
    hipMemsetAsync(agg, 0, (size_t)NN * HH * 4, stream);
    hipMemsetAsync(stats, 0, 256 * 4, stream);
    k_edge_v5<<<NBLK, 256, 0, stream>>>(hs2, hd2, efp, src_s, dst_s, Web, agg);
    k_bn_stats<<<1024, 256, 0, stream>>>(agg, stats);
    k_bn_fin<<<1, 128, 0, stream>>>(stats, bn_gamma + i * HH, bn_beta + i * HH);
    k_update<<<2048, 256, 0, stream>>>(h, agg, stats);
  }

  hipMemsetAsync(g, 0, (size_t)BB * HH * 4, stream);
  hipMemsetAsync(gcnt, 0, BB * 4, stream);
  k_pool<<<256, 128, 0, stream>>>(h, batch, g, gcnt);
  k_final<<<1, 256, 0, stream>>>(g, gcnt, fc1_w, fc1_b, fc_bn_gamma, fc_bn_beta,
                                 out_w, out_b, (float*)d_out);
}

// Round 8
// 2033.148 us; speedup vs baseline: 1.5422x; 1.0464x over previous
//
#include <hip/hip_runtime.h>
#include <hip/hip_bf16.h>

#define NN 100000
#define EE 1600000
#define HH 128
#define NDIM 91
#define EDIM 20
#define BB 128
#define EPSF 1e-5f
#define NBLK 4096
#define PER 400                 // edges per block (4 kg-subranges of 100)
#define ECAP (NBLK * PER)       // 1,638,400 (padded)
#define LN2I 1.44269504f

typedef __attribute__((ext_vector_type(8))) short short8v;
typedef __attribute__((ext_vector_type(4))) float f32x4;

__device__ __forceinline__ short f2bs(float x) {
  __hip_bfloat16 b = __float2bfloat16(x);
  return *reinterpret_cast<short*>(&b);
}
__device__ __forceinline__ float bl(unsigned int u) {  // lo bf16 -> f32
  union { unsigned int i; float f; } x; x.i = u << 16; return x.f;
}
__device__ __forceinline__ float bh(unsigned int u) {  // hi bf16 -> f32
  union { unsigned int i; float f; } x; x.i = u & 0xffff0000u; return x.f;
}

// ---------------- embed: h = nf @ W + b  (N x 91 @ 91 x 128) ----------------
__global__ __launch_bounds__(256) void k_embed(const float* __restrict__ nf,
                                               const float* __restrict__ W,
                                               const float* __restrict__ b,
                                               float* __restrict__ h) {
  __shared__ float w_s[NDIM * HH];
  __shared__ float b_s[HH];
  __shared__ float a_s[16 * 92];
  for (int i = threadIdx.x; i < NDIM * HH; i += 256) w_s[i] = W[i];
  if (threadIdx.x < HH) b_s[threadIdx.x] = b[threadIdx.x];
  __syncthreads();
  int col = threadIdx.x & 127, rs = threadIdx.x >> 7;
  for (int base = blockIdx.x * 16; base < NN; base += gridDim.x * 16) {
    int nrows = min(16, NN - base);
    int tot = nrows * NDIM;
    for (int i = threadIdx.x; i < tot; i += 256) {
      int r = i / NDIM;
      a_s[r * 92 + (i - r * NDIM)] = nf[(size_t)base * NDIM + i];
    }
    __syncthreads();
    float acc[8];
#pragma unroll
    for (int r = 0; r < 8; r++) acc[r] = 0.f;
    for (int k = 0; k < NDIM; k++) {
      float w = w_s[k * HH + col];
#pragma unroll
      for (int r = 0; r < 8; r++) acc[r] += a_s[(rs * 8 + r) * 92 + k] * w;
    }
#pragma unroll
    for (int r = 0; r < 8; r++) {
      int row = base + rs * 8 + r;
      if (row < NN) h[(size_t)row * HH + col] = acc[r] + b_s[col];
    }
    __syncthreads();
  }
}

// ------- weight transpose+cast: wt[mat][col][k] = W_mat[k*256+col] (bf16) ---
__global__ __launch_bounds__(256) void k_w2bf(const float* __restrict__ Wsrc,
                                              const float* __restrict__ Wdst,
                                              short* __restrict__ wt) {
  int i = blockIdx.x * 256 + threadIdx.x;  // 0..65535
  if (i >= 2 * 256 * 128) return;
  int mat = i >> 15;
  int r = (i >> 7) & 255;
  int k = i & 127;
  const float* W = mat ? Wdst : Wsrc;
  wt[i] = f2bs(W[k * 256 + r]);
}

// --- edge-weight: Web[c][k] bf16 (k=20 -> bias, pad 0), scaled:
// --- gate cols (c<128) * -1/ln2, soft cols * +1/ln2 (exp2 formulation) ------
__global__ __launch_bounds__(256) void k_we2bf(const float* __restrict__ We,
                                               const float* __restrict__ bias,
                                               short* __restrict__ Web) {
  int i = blockIdx.x * 256 + threadIdx.x;  // 0..8191
  if (i >= 256 * 32) return;
  int c = i >> 5, k = i & 31;
  float v = (k < EDIM) ? We[k * 256 + c] : (k == EDIM ? bias[c] : 0.f);
  float sc = (c < 128) ? -LN2I : LN2I;
  Web[i] = f2bs(v * sc);
}

// ------------- node_mm (merged mats + optional fused BN-update) ------------
// If apply: hnew = relu(h + agg*stats[c] + stats[128+c]) written back to h,
// used as the A operand. Produces hs2 AND hd2 (paired-column layout):
// slot m(c) = (c>>5)*32 + ((c&15)<<1) + ((c>>4)&1); word = pack(gate,soft).
__global__ __launch_bounds__(256) void k_node_mm(float* __restrict__ h,
                                                 const float* __restrict__ agg,
                                                 const float* __restrict__ stats,
                                                 const short* __restrict__ wt,
                                                 unsigned int* __restrict__ hs2,
                                                 unsigned int* __restrict__ hd2,
                                                 int apply) {
  __shared__ short hlds[64 * 128];  // 16 KB bf16 A-tile
  __shared__ float st_s[256];
  int base = blockIdx.x * 64;
  int t = threadIdx.x;
  if (apply) {
    if (t < 256) st_s[t] = stats[t];
    __syncthreads();
  }
#pragma unroll
  for (int p = 0; p < 4; p++) {
    int e0 = (p * 256 + t) * 8;
    int row = e0 >> 7, col = e0 & 127;
    int gr = base + row;
    float4 f0 = make_float4(0.f, 0.f, 0.f, 0.f), f1 = f0;
    if (gr < NN) {
      f0 = *(const float4*)&h[(size_t)gr * 128 + col];
      f1 = *(const float4*)&h[(size_t)gr * 128 + col + 4];
      if (apply) {
        float4 a0 = *(const float4*)&agg[(size_t)gr * 128 + col];
        float4 a1 = *(const float4*)&agg[(size_t)gr * 128 + col + 4];
        f0.x = fmaxf(f0.x + a0.x * st_s[col] + st_s[128 + col], 0.f);
        f0.y = fmaxf(f0.y + a0.y * st_s[col + 1] + st_s[129 + col], 0.f);
        f0.z = fmaxf(f0.z + a0.z * st_s[col + 2] + st_s[130 + col], 0.f);
        f0.w = fmaxf(f0.w + a0.w * st_s[col + 3] + st_s[131 + col], 0.f);
        f1.x = fmaxf(f1.x + a1.x * st_s[col + 4] + st_s[132 + col], 0.f);
        f1.y = fmaxf(f1.y + a1.y * st_s[col + 5] + st_s[133 + col], 0.f);
        f1.z = fmaxf(f1.z + a1.z * st_s[col + 6] + st_s[134 + col], 0.f);
        f1.w = fmaxf(f1.w + a1.w * st_s[col + 7] + st_s[135 + col], 0.f);
        *(float4*)&h[(size_t)gr * 128 + col] = f0;
        *(float4*)&h[(size_t)gr * 128 + col + 4] = f1;
      }
    }
    short8v u;
    u[0] = f2bs(f0.x); u[1] = f2bs(f0.y); u[2] = f2bs(f0.z); u[3] = f2bs(f0.w);
    u[4] = f2bs(f1.x); u[5] = f2bs(f1.y); u[6] = f2bs(f1.z); u[7] = f2bs(f1.w);
    *(short8v*)&hlds[e0] = u;
  }
  __syncthreads();
  int w = t >> 6, l = t & 63;
  int cl = l & 15, kg = l >> 4;
  short8v a[4];
#pragma unroll
  for (int kk = 0; kk < 4; kk++)
    a[kk] = *(const short8v*)&hlds[(w * 16 + cl) * 128 + kk * 32 + kg * 8];
#pragma unroll
  for (int mat = 0; mat < 2; mat++) {
    const short* wtm = wt + mat * 256 * 128;
    unsigned int* out = mat ? hd2 : hs2;
    f32x4 acc[16];
#pragma unroll
    for (int ct = 0; ct < 16; ct++) acc[ct] = (f32x4)(0.f);
#pragma unroll
    for (int ct = 0; ct < 16; ct++) {
#pragma unroll
      for (int kk = 0; kk < 4; kk++) {
        short8v b = *(const short8v*)&wtm[(ct * 16 + cl) * 128 + kk * 32 + kg * 8];
        acc[ct] = __builtin_amdgcn_mfma_f32_16x16x32_bf16(a[kk], b, acc[ct], 0, 0, 0);
      }
    }
    // pair gate col c (ct<8) with soft col c+128 (ct+8); paired-column slot
#pragma unroll
    for (int ct = 0; ct < 8; ct++) {
#pragma unroll
      for (int r = 0; r < 4; r++) {
        int gr = base + w * 16 + kg * 4 + r;
        if (gr < NN) {
          unsigned short g = (unsigned short)f2bs(-LN2I * acc[ct][r]);
          unsigned short s = (unsigned short)f2bs(LN2I * acc[ct + 8][r]);
          int slot = (ct >> 1) * 32 + (cl << 1) + (ct & 1);
          out[(size_t)gr * 128 + slot] = (unsigned int)g | ((unsigned int)s << 16);
        }
      }
    }
  }
}

// ---------------- counting sort by dst: hist, scan, scatter -----------------
__global__ __launch_bounds__(256) void k_hist(const int* __restrict__ dst,
                                              int* __restrict__ cnt) {
  for (int e = blockIdx.x * 256 + threadIdx.x; e < EE; e += gridDim.x * 256)
    atomicAdd(&cnt[dst[e]], 1);
}

__global__ __launch_bounds__(1024) void k_scan(const int* __restrict__ cnt,
                                               int* __restrict__ off) {
  __shared__ int ps[1024];
  int t = threadIdx.x;
  const int R = (NN + 1023) / 1024;
  int b0 = t * R, b1 = min(NN, b0 + R);
  int s = 0;
  for (int i = b0; i < b1; i++) s += cnt[i];
  ps[t] = s;
  __syncthreads();
  for (int d = 1; d < 1024; d <<= 1) {
    int v = (t >= d) ? ps[t - d] : 0;
    __syncthreads();
    ps[t] += v;
    __syncthreads();
  }
  int run = (t == 0) ? 0 : ps[t - 1];
  for (int i = b0; i < b1; i++) {
    off[i] = run;
    run += cnt[i];
  }
}

// scatter: sorted idx arrays + ef rows pre-cast to bf16 [32] (k20=1.0 bias hook)
__global__ __launch_bounds__(256) void k_scatter(const int* __restrict__ src,
                                                 const int* __restrict__ dst,
                                                 const float* __restrict__ ef,
                                                 int* __restrict__ off,
                                                 int* __restrict__ src_s,
                                                 int* __restrict__ dst_s,
                                                 short* __restrict__ efp) {
  for (int e = blockIdx.x * 256 + threadIdx.x; e < EE; e += gridDim.x * 256) {
    int d = dst[e];
    int pos = atomicAdd(&off[d], 1);
    src_s[pos] = src[e];
    dst_s[pos] = d;
    const float4* in = (const float4*)&ef[(size_t)e * EDIM];
    float4 q0 = in[0], q1 = in[1], q2 = in[2], q3 = in[3], q4 = in[4];
    short8v u0, u1, u2, u3;
    u0[0] = f2bs(q0.x); u0[1] = f2bs(q0.y); u0[2] = f2bs(q0.z); u0[3] = f2bs(q0.w);
    u0[4] = f2bs(q1.x); u0[5] = f2bs(q1.y); u0[6] = f2bs(q1.z); u0[7] = f2bs(q1.w);
    u1[0] = f2bs(q2.x); u1[1] = f2bs(q2.y); u1[2] = f2bs(q2.z); u1[3] = f2bs(q2.w);
    u1[4] = f2bs(q3.x); u1[5] = f2bs(q3.y); u1[6] = f2bs(q3.z); u1[7] = f2bs(q3.w);
    u2[0] = f2bs(q4.x); u2[1] = f2bs(q4.y); u2[2] = f2bs(q4.z); u2[3] = f2bs(q4.w);
    u2[4] = f2bs(1.0f); u2[5] = 0; u2[6] = 0; u2[7] = 0;
    u3 = (short8v)(short)0;
    short8v* op = (short8v*)&efp[(size_t)pos * 32];
    op[0] = u0; op[1] = u1; op[2] = u2; op[3] = u3;
  }
}

// pad tail [EE, ECAP): dst=-2 sentinel, zero ef rows
__global__ __launch_bounds__(256) void k_padtail(int* __restrict__ src_s,
                                                 int* __restrict__ dst_s,
                                                 short* __restrict__ efp) {
  int e = EE + blockIdx.x * 256 + threadIdx.x;
  if (e >= ECAP) return;
  src_s[e] = 0;
  dst_s[e] = -2;
  short8v z = (short8v)(short)0;
  short8v* op = (short8v*)&efp[(size_t)e * 32];
  op[0] = z; op[1] = z; op[2] = z; op[3] = z;
}

// ---- edge kernel v6: barrier-free, zero LDS, paired uint2 gathers.
// Wave w owns cols (w*32+cl, +16). 4 MFMAs per 16-edge tile give z_gate/z_soft
// in-register. Per-lane contiguous edge runs -> register segment sums.
// msg' = log2(1+2^zs') * rcp(1+2^zgN) = msg/ln2 (BN absorbs the scale).
__global__ __launch_bounds__(256) void k_edge_v6(
    const unsigned int* __restrict__ hs2, const unsigned int* __restrict__ hd2,
    const short* __restrict__ efp, const int* __restrict__ srcp,
    const int* __restrict__ dstp, const short* __restrict__ Web,
    float* __restrict__ agg) {
  const int i0 = blockIdx.x * PER;
  int t = threadIdx.x;
  int w = t >> 6, l = t & 63, cl = l & 15, kg = l >> 4;
  int c0 = w * 32 + cl, c1 = c0 + 16;
  int pairoff = w * 32 + (cl << 1);
  short8v bg0 = *(const short8v*)&Web[c0 * 32 + kg * 8];
  short8v bg1 = *(const short8v*)&Web[c1 * 32 + kg * 8];
  short8v bs0 = *(const short8v*)&Web[(128 + c0) * 32 + kg * 8];
  short8v bs1 = *(const short8v*)&Web[(128 + c1) * 32 + kg * 8];
  int cur = -1;
  float acc0 = 0.f, acc1 = 0.f;
  float hg0 = 0.f, hp0 = 0.f, hg1 = 0.f, hp1 = 0.f;
  const int o_a_base = i0 + (cl >> 2) * 100 + (cl & 3);
  const int o_e_base = i0 + kg * 100;
  for (int it = 0; it < 25; ++it) {
    int off4 = it * 4;
    short8v a = *(const short8v*)&efp[(size_t)(o_a_base + off4) * 32 + kg * 8];
    f32x4 zgv0 = __builtin_amdgcn_mfma_f32_16x16x32_bf16(a, bg0, (f32x4)(0.f), 0, 0, 0);
    f32x4 zgv1 = __builtin_amdgcn_mfma_f32_16x16x32_bf16(a, bg1, (f32x4)(0.f), 0, 0, 0);
    f32x4 zsv0 = __builtin_amdgcn_mfma_f32_16x16x32_bf16(a, bs0, (f32x4)(0.f), 0, 0, 0);
    f32x4 zsv1 = __builtin_amdgcn_mfma_f32_16x16x32_bf16(a, bs1, (f32x4)(0.f), 0, 0, 0);
    int o_e = o_e_base + off4;
    int4 s4 = *(const int4*)&srcp[o_e];
    int4 d4 = *(const int4*)&dstp[o_e];
    int ss[4] = {s4.x, s4.y, s4.z, s4.w};
    int dd[4] = {d4.x, d4.y, d4.z, d4.w};
#pragma unroll
    for (int r = 0; r < 4; ++r) {
      int s = ss[r], d = dd[r];
      if (d != cur) {  // per-lane divergent, rare (~1/16 edges)
        if (cur >= 0) {
          atomicAdd(&agg[cur * HH + c0], acc0);
          atomicAdd(&agg[cur * HH + c1], acc1);
        }
        acc0 = 0.f; acc1 = 0.f;
        cur = d;
        if (d >= 0) {
          uint2 x = *(const uint2*)&hd2[((size_t)d << 7) + pairoff];
          hg0 = bl(x.x); hp0 = bh(x.x);
          hg1 = bl(x.y); hp1 = bh(x.y);
        }
      }
      uint2 u = *(const uint2*)&hs2[((size_t)s << 7) + pairoff];
      float zgN0 = zgv0[r] + bl(u.x) + hg0;
      float zsp0 = zsv0[r] + bh(u.x) + hp0;
      float zgN1 = zgv1[r] + bl(u.y) + hg1;
      float zsp1 = zsv1[r] + bh(u.y) + hp1;
      float sp0 = __builtin_amdgcn_logf(1.f + __builtin_amdgcn_exp2f(zsp0));
      float sp1 = __builtin_amdgcn_logf(1.f + __builtin_amdgcn_exp2f(zsp1));
      acc0 += sp0 * __builtin_amdgcn_rcpf(1.f + __builtin_amdgcn_exp2f(zgN0));
      acc1 += sp1 * __builtin_amdgcn_rcpf(1.f + __builtin_amdgcn_exp2f(zgN1));
    }
  }
  if (cur >= 0) {
    atomicAdd(&agg[cur * HH + c0], acc0);
    atomicAdd(&agg[cur * HH + c1], acc1);
  }
}

// ---------------- BN stats: per-column sum & sumsq over N rows --------------
__global__ __launch_bounds__(256) void k_bn_stats(const float* __restrict__ agg,
                                                  float* __restrict__ stats) {
  int col = threadIdx.x & 127, hlf = threadIdx.x >> 7;
  float s = 0.f, sq = 0.f;
  for (int row = blockIdx.x * 2 + hlf; row < NN; row += gridDim.x * 2) {
    float v = agg[(size_t)row * HH + col];
    s += v; sq += v * v;
  }
  __shared__ float ls[256], lq[256];
  ls[threadIdx.x] = s; lq[threadIdx.x] = sq;
  __syncthreads();
  if (hlf == 0) {
    atomicAdd(&stats[col], ls[col] + ls[col + 128]);
    atomicAdd(&stats[128 + col], lq[col] + lq[col + 128]);
  }
}

__global__ void k_bn_fin(float* stats, const float* __restrict__ gam,
                         const float* __restrict__ bet) {
  int c = threadIdx.x;
  if (c >= HH) return;
  float mean = stats[c] / (float)NN;
  float var = stats[HH + c] / (float)NN - mean * mean;
  float sc = rsqrtf(var + EPSF) * gam[c];
  stats[c] = sc;
  stats[HH + c] = bet[c] - mean * sc;
}

// ---------------- h = relu(h + agg*scale + shift)  (last layer only) --------
__global__ __launch_bounds__(256) void k_update(float* __restrict__ h,
                                                const float* __restrict__ agg,
                                                const float* __restrict__ stats) {
  for (size_t i = (size_t)blockIdx.x * blockDim.x + threadIdx.x; i < (size_t)NN * HH;
       i += (size_t)gridDim.x * blockDim.x) {
    int c = (int)(i & 127);
    float v = h[i] + agg[i] * stats[c] + stats[128 + c];
    h[i] = fmaxf(v, 0.f);
  }
}

// ---------------- pooling: contiguous chunk per block, register acc ---------
__global__ void k_pool(const float* __restrict__ h, const int* __restrict__ batch,
                       float* __restrict__ g, float* __restrict__ gcnt) {
  int col = threadIdx.x;  // 128
  int chunk = (NN + gridDim.x - 1) / gridDim.x;
  int n0 = blockIdx.x * chunk, n1 = min(NN, n0 + chunk);
  if (n0 >= n1) return;
  int cur = batch[n0];
  float acc = 0.f, cnt = 0.f;
  for (int n = n0; n < n1; n++) {
    int bb = batch[n];
    if (bb != cur) {
      atomicAdd(&g[cur * HH + col], acc);
      if (col == 0) atomicAdd(&gcnt[cur], cnt);
      acc = 0.f; cnt = 0.f; cur = bb;
    }
    acc += h[(size_t)n * HH + col];
    cnt += 1.f;
  }
  atomicAdd(&g[cur * HH + col], acc);
  if (col == 0) atomicAdd(&gcnt[cur], cnt);
}

// ---------------- final head: mean-pool norm, fc1, BN, relu, out ------------
__global__ __launch_bounds__(256) void k_final(float* __restrict__ g,
                                               const float* __restrict__ gcnt,
                                               const float* __restrict__ fc1w,
                                               const float* __restrict__ fc1b,
                                               const float* __restrict__ gam,
                                               const float* __restrict__ bet,
                                               const float* __restrict__ ow,
                                               const float* __restrict__ ob,
                                               float* __restrict__ out) {
  __shared__ float w_s[HH * HH];
  __shared__ float y_s[BB * HH];
  __shared__ float ls[256], lq[256];
  for (int i = threadIdx.x; i < HH * HH; i += 256) w_s[i] = fc1w[i];
  for (int i = threadIdx.x; i < BB * HH; i += 256) {
    int r = i >> 7;
    g[i] = g[i] / fmaxf(gcnt[r], 1.f);
  }
  __syncthreads();
  int c = threadIdx.x & 127, h2 = threadIdx.x >> 7;
  for (int rr = 0; rr < 64; rr++) {
    int r = h2 * 64 + rr;
    float acc = fc1b[c];
    for (int k = 0; k < HH; k++) acc += g[r * HH + k] * w_s[k * HH + c];
    y_s[r * HH + c] = acc;
  }
  __syncthreads();
  float s = 0.f, sq = 0.f;
  for (int rr = 0; rr < 64; rr++) {
    float v = y_s[(h2 * 64 + rr) * HH + c];
    s += v; sq += v * v;
  }
  ls[threadIdx.x] = s; lq[threadIdx.x] = sq;
  __syncthreads();
  if (h2 == 0) {
    float ss = ls[c] + ls[c + 128], qq = lq[c] + lq[c + 128];
    float mean = ss / (float)BB, var = qq / (float)BB - mean * mean;
    float sc = rsqrtf(var + EPSF) * gam[c];
    ls[c] = sc;
    lq[c] = bet[c] - mean * sc;
  }
  __syncthreads();
  for (int rr = 0; rr < 64; rr++) {
    int r = h2 * 64 + rr;
    y_s[r * HH + c] = fmaxf(y_s[r * HH + c] * ls[c] + lq[c], 0.f);
  }
  __syncthreads();
  int r2 = threadIdx.x >> 1, hf = threadIdx.x & 1;
  float acc = 0.f;
  for (int k = hf * 64; k < hf * 64 + 64; k++) acc += y_s[r2 * HH + k] * ow[k];
  __syncthreads();
  ls[threadIdx.x] = acc;
  __syncthreads();
  if (hf == 0) out[r2] = ls[threadIdx.x] + ls[threadIdx.x + 1] + ob[0];
}

extern "C" void kernel_launch(void* const* d_in, const int* in_sizes, int n_in,
                              void* d_out, int out_size, void* d_ws, size_t ws_size,
                              hipStream_t stream) {
  (void)in_sizes; (void)n_in; (void)out_size; (void)ws_size;
  const float* node_feats = (const float*)d_in[0];
  const int* edge_index = (const int*)d_in[1];
  const float* edge_feats = (const float*)d_in[2];
  const int* batch = (const int*)d_in[3];
  const float* embed_w = (const float*)d_in[4];
  const float* embed_b = (const float*)d_in[5];
  const float* conv_wsrc = (const float*)d_in[6];
  const float* conv_wdst = (const float*)d_in[7];
  const float* conv_we = (const float*)d_in[8];
  const float* conv_b = (const float*)d_in[9];
  const float* bn_gamma = (const float*)d_in[10];
  const float* bn_beta = (const float*)d_in[11];
  const float* fc1_w = (const float*)d_in[12];
  const float* fc1_b = (const float*)d_in[13];
  const float* fc_bn_gamma = (const float*)d_in[14];
  const float* fc_bn_beta = (const float*)d_in[15];
  const float* out_w = (const float*)d_in[16];
  const float* out_b = (const float*)d_in[17];

  char* ws = (char*)d_ws;
  size_t o = 0;
  float* h = (float*)(ws + o);              o += (size_t)NN * HH * 4;      // 51.2 MB
  unsigned int* hs2 = (unsigned int*)(ws + o); o += (size_t)NN * 128 * 4;  // 51.2 MB
  unsigned int* hd2 = (unsigned int*)(ws + o); o += (size_t)NN * 128 * 4;  // 51.2 MB
  float* agg = (float*)(ws + o);            o += (size_t)NN * HH * 4;      // 51.2 MB
  short* efp = (short*)(ws + o);            o += (size_t)ECAP * 32 * 2;    // 104.9 MB
  int* src_s = (int*)(ws + o);              o += (size_t)ECAP * 4;         // 6.6 MB
  int* dst_s = (int*)(ws + o);              o += (size_t)ECAP * 4;         // 6.6 MB
  int* cnt = (int*)(ws + o);                o += (size_t)NN * 4;
  int* off = (int*)(ws + o);                o += (size_t)NN * 4;
  short* wt = (short*)(ws + o);             o += (size_t)2 * 256 * 128 * 2;
  short* Web = (short*)(ws + o);            o += (size_t)256 * 32 * 2;
  float* stats = (float*)(ws + o);          o += 256 * 4;
  float* g = (float*)(ws + o);              o += (size_t)BB * HH * 4;
  float* gcnt = (float*)(ws + o);           o += BB * 4;

  const int* src = edge_index;
  const int* dst = edge_index + EE;

  // one-time: counting sort by dst + ef pre-cast/pad (reused by all layers)
  hipMemsetAsync(cnt, 0, (size_t)NN * 4, stream);
  k_hist<<<2048, 256, 0, stream>>>(dst, cnt);
  k_scan<<<1, 1024, 0, stream>>>(cnt, off);
  k_scatter<<<2048, 256, 0, stream>>>(src, dst, edge_feats, off, src_s, dst_s, efp);
  k_padtail<<<(ECAP - EE + 255) / 256, 256, 0, stream>>>(src_s, dst_s, efp);

  k_embed<<<512, 256, 0, stream>>>(node_feats, embed_w, embed_b, h);

  for (int i = 0; i < 3; i++) {
    k_w2bf<<<256, 256, 0, stream>>>(conv_wsrc + (size_t)i * HH * 256,
                                    conv_wdst + (size_t)i * HH * 256, wt);
    k_we2bf<<<32, 256, 0, stream>>>(conv_we + (size_t)i * EDIM * 256,
                                    conv_b + (size_t)i * 256, Web);
    // fused: applies previous layer's BN-update to h (i>0), then hs2/hd2
    k_node_mm<<<(NN + 63) / 64, 256, 0, stream>>>(h, agg, stats, wt, hs2, hd2,
                                                  i > 0 ? 1 : 0);
    hipMemsetAsync(agg, 0, (size_t)NN * HH * 4, stream);
    hipMemsetAsync(stats, 0, 256 * 4, stream);
    k_edge_v6<<<NBLK, 256, 0, stream>>>(hs2, hd2, efp, src_s, dst_s, Web, agg);
    k_bn_stats<<<1024, 256, 0, stream>>>(agg, stats);
    k_bn_fin<<<1, 128, 0, stream>>>(stats, bn_gamma + i * HH, bn_beta + i * HH);
  }
  // final layer's BN-update (not consumed by a following node_mm)
  k_update<<<2048, 256, 0, stream>>>(h, agg, stats);

  hipMemsetAsync(g, 0, (size_t)BB * HH * 4, stream);
  hipMemsetAsync(gcnt, 0, BB * 4, stream);
  k_pool<<<256, 128, 0, stream>>>(h, batch, g, gcnt);
  k_final<<<1, 256, 0, stream>>>(g, gcnt, fc1_w, fc1_b, fc_bn_gamma, fc_bn_beta,
                                 out_w, out_b, (float*)d_out);
}